// Round 2
// baseline (235.390 us; speedup 1.0000x reference)
//
#include <hip/hip_runtime.h>

#define NCOLS 1024  // N fixed at 1024 per reference setup

// Native clang vector type — accepted by __builtin_nontemporal_load/store.
typedef float vfloat4 __attribute__((ext_vector_type(4)));

// Two INDEPENDENT rows per wave (rows 2w, 2w+1 — always in the same input
// tensor since rows_per_input is even). 8 plain cached loads issue up front;
// the two butterfly reduction chains interleave (DS pipe overlaps them), and
// 8 NT stores stream out. No loop-carried state, no LDS, no __syncthreads.
//
// vs R0/R1: loads are NOT nontemporal (streamed reads gain nothing from NT
// but can lose TCC request-merging; the 6.29 TB/s copy reference uses plain
// loads). Stores stay NT (avoid write-allocate pollution of L2/L3).
__global__ __launch_bounds__(256) void Normalizer_row_kernel(
    const float* __restrict__ a0, const float* __restrict__ a1,
    float* __restrict__ out, int rows_per_input) {
    const int lane  = threadIdx.x & 63;
    const int gwave = (blockIdx.x * 256 + threadIdx.x) >> 6;  // global wave id
    const int r0    = gwave * 2;  // this wave owns rows r0 and r0+1

    const float* src = (r0 < rows_per_input)
        ? a0 + (size_t)r0 * NCOLS
        : a1 + (size_t)(r0 - rows_per_input) * NCOLS;
    const vfloat4* s4 = reinterpret_cast<const vfloat4*>(src);

    // Row A = r0 (vfloat4 indices 0..255), Row B = r0+1 (indices 256..511).
    // 8 independent 16B loads — all in flight before any consumption.
    vfloat4 x0 = s4[lane];
    vfloat4 x1 = s4[lane + 64];
    vfloat4 x2 = s4[lane + 128];
    vfloat4 x3 = s4[lane + 192];
    vfloat4 y0 = s4[lane + 256];
    vfloat4 y1 = s4[lane + 320];
    vfloat4 y2 = s4[lane + 384];
    vfloat4 y3 = s4[lane + 448];

    // Per-lane partials (independent trees), then interleaved 6-step
    // butterflies — the two __shfl_xor chains pipeline on the DS unit,
    // halving the per-row serial-latency exposure.
    float sa = ((x0.x + x0.y) + (x0.z + x0.w)) + ((x1.x + x1.y) + (x1.z + x1.w))
             + ((x2.x + x2.y) + (x2.z + x2.w)) + ((x3.x + x3.y) + (x3.z + x3.w));
    float sb = ((y0.x + y0.y) + (y0.z + y0.w)) + ((y1.x + y1.y) + (y1.z + y1.w))
             + ((y2.x + y2.y) + (y2.z + y2.w)) + ((y3.x + y3.y) + (y3.z + y3.w));
#pragma unroll
    for (int off = 32; off > 0; off >>= 1) {
        sa += __shfl_xor(sa, off, 64);
        sb += __shfl_xor(sb, off, 64);
    }

    float inva = 1.0f / sa;
    float invb = 1.0f / sb;
    if (!isfinite(inva)) inva = 0.0f;  // nan/inf -> 0 per reference
    if (!isfinite(invb)) invb = 0.0f;

    // Output is the two normalized tensors concatenated -> dst is row-major.
    vfloat4* d4 = reinterpret_cast<vfloat4*>(out + (size_t)r0 * NCOLS);
    __builtin_nontemporal_store(x0 * inva, &d4[lane]);
    __builtin_nontemporal_store(x1 * inva, &d4[lane + 64]);
    __builtin_nontemporal_store(x2 * inva, &d4[lane + 128]);
    __builtin_nontemporal_store(x3 * inva, &d4[lane + 192]);
    __builtin_nontemporal_store(y0 * invb, &d4[lane + 256]);
    __builtin_nontemporal_store(y1 * invb, &d4[lane + 320]);
    __builtin_nontemporal_store(y2 * invb, &d4[lane + 384]);
    __builtin_nontemporal_store(y3 * invb, &d4[lane + 448]);
}

extern "C" void kernel_launch(void* const* d_in, const int* in_sizes, int n_in,
                              void* d_out, int out_size, void* d_ws, size_t ws_size,
                              hipStream_t stream) {
    const float* a0 = (const float*)d_in[0];
    const float* a1 = (const float*)d_in[1];
    float* out = (float*)d_out;

    const int rows_per_input = in_sizes[0] / NCOLS;   // 16 * 1024 = 16384
    const int total_rows = 2 * rows_per_input;        // 32768
    // 4 waves/block x 2 rows/wave = 8 rows per block.
    const int blocks = total_rows / 8;                // 4096

    Normalizer_row_kernel<<<blocks, 256, 0, stream>>>(a0, a1, out, rows_per_input);
}